// Round 1
// baseline (107.289 us; speedup 1.0000x reference)
//
#include <hip/hip_runtime.h>
#include <math.h>

namespace {
constexpr int N_  = 2;
constexpr int SF_ = 2;
constexpr int KP_ = 8;
constexpr int C_  = 3;
constexpr int H_  = 64;
constexpr int W_  = 64;
constexpr int NBINS_ = 256;
constexpr int B_   = N_ * SF_ * KP_;   // 32 patches
constexpr int PIX_ = H_ * W_;          // 4096
constexpr int CH_  = 8;                // pixel chunks per (b,c)
constexpr int CHPIX_ = PIX_ / CH_;     // 512
constexpr int D_   = C_ * NBINS_;      // 768
constexpr int ROWS_ = N_ * KP_ * SF_;  // 32
constexpr int PADD_ = D_ + 1;          // 769 -> row maps to distinct LDS bank
}

// ---------------------------------------------------------------------------
// Kernel A: fused gaussian-mask * image -> soft histogram (256 bins)
// grid = (CH_, C_, B_), block = 256.
// Layout: each wave owns a 128-pixel subset of the 512-pixel chunk and ALL
// 256 bins (lane = bin%64, j = bin/64). Pixel value broadcast from LDS;
// __any() skips bin-groups with no lane within 0.03 of the pixel value
// (contribution there < 3e-9 summed -> negligible vs 1e-2 threshold).
// ---------------------------------------------------------------------------
__global__ __launch_bounds__(256) void pcl_hist(const float* __restrict__ coords,
                                                const float* __restrict__ images,
                                                float* __restrict__ hist) {
  __shared__ float xs[CHPIX_];
  __shared__ float shist[NBINS_];

  const int chunk = blockIdx.x;
  const int c     = blockIdx.y;
  const int b     = blockIdx.z;       // (n*SF+sf)*KP + kp
  const int tid   = threadIdx.x;

  const int kp  = b & (KP_ - 1);
  const int sfn = b >> 3;             // n*SF + sf

  const float cx = coords[(sfn * KP_ + kp) * 2 + 0] * (float)W_;
  const float cy = coords[(sfn * KP_ + kp) * 2 + 1] * (float)H_;

  shist[tid] = 0.0f;

  // ---- stage 512 pixel values (image * gaussian mask) into LDS ----
  const float* img = images + (size_t)(sfn * C_ + c) * PIX_;
  const int p0 = chunk * CHPIX_ + tid * 2;
  const float2 iv = *reinterpret_cast<const float2*>(img + p0);
  const float inv2s2 = 1.0f / 72.0f;  // 1/(2*std^2), std = 6
  const float hh = (float)(p0 >> 6);
  const float ww = (float)(p0 & 63);
  const float dy  = hh - cy;
  const float dx0 = ww - cx;
  const float dx1 = dx0 + 1.0f;
  xs[tid * 2 + 0] = iv.x * expf(-(dx0 * dx0 + dy * dy) * inv2s2);
  xs[tid * 2 + 1] = iv.y * expf(-(dx1 * dx1 + dy * dy) * inv2s2);
  __syncthreads();

  const int lane = tid & 63;
  const int wv   = tid >> 6;
  const float c0 = ((float)lane + 0.5f) * (1.0f / 256.0f);
  const float c1 = c0 + 0.25f;
  const float c2 = c0 + 0.50f;
  const float c3 = c0 + 0.75f;
  const float invBW = 1000.0f;        // 1/bandwidth
  const float hd = 1.0f / 512.0f;     // delta/2

  float sum0 = 0.f, sum1 = 0.f, sum2 = 0.f, sum3 = 0.f;
  const float* wx = xs + wv * (CHPIX_ / 4);

  for (int p = 0; p < CHPIX_ / 4; ++p) {
    const float x = wx[p];            // broadcast: all lanes same address
    {
      const float d = x - c0;
      if (__any(fabsf(d) < 0.03f)) {
        const float s1 = 1.0f / (1.0f + expf(-(d + hd) * invBW));
        const float s2 = 1.0f / (1.0f + expf(-(d - hd) * invBW));
        sum0 += s1 - s2;
      }
    }
    {
      const float d = x - c1;
      if (__any(fabsf(d) < 0.03f)) {
        const float s1 = 1.0f / (1.0f + expf(-(d + hd) * invBW));
        const float s2 = 1.0f / (1.0f + expf(-(d - hd) * invBW));
        sum1 += s1 - s2;
      }
    }
    {
      const float d = x - c2;
      if (__any(fabsf(d) < 0.03f)) {
        const float s1 = 1.0f / (1.0f + expf(-(d + hd) * invBW));
        const float s2 = 1.0f / (1.0f + expf(-(d - hd) * invBW));
        sum2 += s1 - s2;
      }
    }
    {
      const float d = x - c3;
      if (__any(fabsf(d) < 0.03f)) {
        const float s1 = 1.0f / (1.0f + expf(-(d + hd) * invBW));
        const float s2 = 1.0f / (1.0f + expf(-(d - hd) * invBW));
        sum3 += s1 - s2;
      }
    }
  }

  atomicAdd(&shist[lane +   0], sum0);
  atomicAdd(&shist[lane +  64], sum1);
  atomicAdd(&shist[lane + 128], sum2);
  atomicAdd(&shist[lane + 192], sum3);
  __syncthreads();

  atomicAdd(&hist[(size_t)(b * C_ + c) * NBINS_ + tid], shist[tid]);
}

// ---------------------------------------------------------------------------
// Kernel B: zero bin0, normalize rows, cosine-sim matrix, contrastive loss.
// Single block, 256 threads. rows: (N, KP*SF, 768), row i = kp*SF + sf.
// ---------------------------------------------------------------------------
__global__ __launch_bounds__(256) void pcl_loss(const float* __restrict__ hist,
                                                float* __restrict__ out) {
  __shared__ float rows[ROWS_][PADD_];   // ~98.4 KB
  __shared__ float invn[ROWS_];
  __shared__ float pw[4], nw[4];

  const int tid = threadIdx.x;

  // load + transpose + kill bin 0
  for (int idx = tid; idx < ROWS_ * D_; idx += 256) {
    const int r = idx / D_;
    const int d = idx - r * D_;
    const int n  = r >> 4;
    const int i  = r & 15;
    const int kp = i >> 1;
    const int sf = i & 1;
    const int c   = d >> 8;
    const int bin = d & 255;
    const int b = (n * SF_ + sf) * KP_ + kp;
    rows[r][d] = (bin == 0) ? 0.0f : hist[(b * C_ + c) * NBINS_ + bin];
  }
  __syncthreads();

  // row norms: 8 threads per row
  {
    const int r  = tid >> 3;
    const int s8 = tid & 7;
    float s = 0.0f;
    for (int d = s8; d < D_; d += 8) {
      const float v = rows[r][d];
      s += v * v;
    }
    s += __shfl_xor(s, 4);
    s += __shfl_xor(s, 2);
    s += __shfl_xor(s, 1);
    if (s8 == 0) invn[r] = 1.0f / (sqrtf(s) + 1e-8f);
  }
  __syncthreads();

  for (int idx = tid; idx < ROWS_ * D_; idx += 256) {
    const int r = idx / D_;
    rows[r][idx - r * D_] *= invn[r];
  }
  __syncthreads();

  // 120 upper-triangle pairs per n (sim symmetric -> x2)
  float pacc = 0.0f, nacc = 0.0f;
  if (tid < 240) {
    const int n  = tid / 120;
    int rem = tid % 120;
    int i = 0;
    while (rem >= 15 - i) { rem -= 15 - i; ++i; }
    const int j = i + 1 + rem;
    const float* ri = rows[n * 16 + i];
    const float* rj = rows[n * 16 + j];
    float s = 0.0f;
    for (int d = 0; d < D_; ++d) s += ri[d] * rj[d];
    if ((i >> 1) == (j >> 1)) {
      pacc = 2.0f * (1.0f - s);                 // same kp, different sf
    } else {
      nacc = 2.0f * fmaxf(s - 0.5f, 0.0f);      // different kp
    }
  }

  const int lane = tid & 63;
  const int wv   = tid >> 6;
  for (int m = 32; m >= 1; m >>= 1) {
    pacc += __shfl_xor(pacc, m);
    nacc += __shfl_xor(nacc, m);
  }
  if (lane == 0) { pw[wv] = pacc; nw[wv] = nacc; }
  __syncthreads();
  if (tid == 0) {
    const float p = pw[0] + pw[1] + pw[2] + pw[3];
    const float g = nw[0] + nw[1] + nw[2] + nw[3];
    // n_pos = 16*N = 32 ; n_neg = 224*N = 448
    out[0] = p * (1.0f / 32.0f) + g * (1.0f / 448.0f);
  }
}

extern "C" void kernel_launch(void* const* d_in, const int* in_sizes, int n_in,
                              void* d_out, int out_size, void* d_ws, size_t ws_size,
                              hipStream_t stream) {
  const float* coords = (const float*)d_in[0];
  const float* images = (const float*)d_in[1];
  float* hist = (float*)d_ws;                       // 32*3*256 floats = 96 KB
  float* out  = (float*)d_out;

  hipMemsetAsync(hist, 0, (size_t)B_ * C_ * NBINS_ * sizeof(float), stream);

  dim3 grid(CH_, C_, B_);
  pcl_hist<<<grid, 256, 0, stream>>>(coords, images, hist);
  pcl_loss<<<1, 256, 0, stream>>>(hist, out);
}

// Round 2
// 56.215 us; speedup vs baseline: 1.9085x; 1.9085x over previous
//
#include <hip/hip_runtime.h>
#include <math.h>

namespace {
constexpr int NBINS_ = 256;
constexpr int C_   = 3;
constexpr int B_   = 32;     // N*SF*KP patches
constexpr int PIX_ = 4096;   // 64*64
constexpr int D_   = 768;    // C*NBINS
constexpr int PADD_ = 772;   // row stride (floats), 16B-aligned
constexpr float XEPS = 1e-7f;
// sigmoid((x - t/256)/0.001) = 1/(1+exp2((t - 256x) * ESC)), ESC = 1000/256 * log2(e)
constexpr float ESC = 5.63552750f;
constexpr float MSC = 0.0200374311f;   // log2(e)/72  (gaussian, std=6)
}

__device__ __forceinline__ float sig_edge(float t_minus_u) {
  float e = __builtin_amdgcn_exp2f(t_minus_u * ESC);
  return __builtin_amdgcn_rcpf(1.0f + e);
}

// ---------------------------------------------------------------------------
// Kernel A: one block per (b, c). Fused gaussian mask * image -> scatter into
// per-wave LDS histograms (telescoped edge sigmoids, +-5 bin window).
// Near-zero pixels (x < 1e-7) are batched: count * k(0) applied once per wave.
// ---------------------------------------------------------------------------
__global__ __launch_bounds__(256) void pcl_hist(const float* __restrict__ coords,
                                                const float* __restrict__ images,
                                                float* __restrict__ hist) {
  __shared__ float shist[4][NBINS_];

  const int c   = blockIdx.x;          // 0..2
  const int b   = blockIdx.y;          // 0..31 = (n*SF+sf)*KP + kp
  const int tid = threadIdx.x;
  const int wv  = tid >> 6;
  const int lane = tid & 63;

  const float cx = coords[b * 2 + 0] * 64.0f;
  const float cy = coords[b * 2 + 1] * 64.0f;
  const int sfn = b >> 3;
  const float* img = images + (size_t)(sfn * C_ + c) * PIX_;

  shist[0][tid] = 0.0f; shist[1][tid] = 0.0f;
  shist[2][tid] = 0.0f; shist[3][tid] = 0.0f;
  __syncthreads();

  const float dx = (float)(tid & 63) - cx;
  const float dx2 = dx * dx;
  int zc = 0;

  for (int i = 0; i < 16; ++i) {
    const float py = (float)(i * 4 + wv);
    const float dy = py - cy;
    const float m = __builtin_amdgcn_exp2f(-(dx2 + dy * dy) * MSC);
    const float x = img[i * 256 + tid] * m;
    if (x < XEPS) {
      ++zc;
    } else {
      const float u = x * 256.0f;          // position in bin units
      int jc = (int)u; if (jc > 255) jc = 255;
      const int jlo = jc - 5;
      float eprev = sig_edge((float)jlo - u);
      #pragma unroll
      for (int s = 1; s <= 11; ++s) {
        const float e = sig_edge((float)(jlo + s) - u);
        const int bin = jlo + s - 1;
        if (bin >= 0 && bin < 256) atomicAdd(&shist[wv][bin], eprev - e);
        eprev = e;
      }
    }
  }

  // batched contribution of near-zero pixels: zf * (E_t(0) - E_{t+1}(0))
  float zf = (float)zc;
  #pragma unroll
  for (int m = 32; m >= 1; m >>= 1) zf += __shfl_xor(zf, m);
  {
    const float E = sig_edge((float)lane);       // edge t = lane at x = 0
    const float En = __shfl_down(E, 1);
    if (lane < 6) atomicAdd(&shist[wv][lane], zf * (E - En));
  }
  __syncthreads();

  hist[(size_t)(b * C_ + c) * NBINS_ + tid] =
      shist[0][tid] + shist[1][tid] + shist[2][tid] + shist[3][tid];
}

// ---------------------------------------------------------------------------
// Kernel B: single block, 1024 threads. Stage rows into LDS (bin0 zeroed at
// stage time), 32-lane row norms, 240 pairs x 4 threads, float4 throughout.
// ---------------------------------------------------------------------------
__global__ __launch_bounds__(1024) void pcl_loss(const float* __restrict__ hist,
                                                 float* __restrict__ out) {
  __shared__ float rows[B_][PADD_];      // ~98.8 KB
  __shared__ float invn[B_];
  __shared__ float wred[16][2];

  const int tid = threadIdx.x;

  // stage 32x768 as float4; zero the 3 bin-0 slots (d = 0, 256, 512)
  #pragma unroll
  for (int k = 0; k < 6; ++k) {
    const int g  = tid + k * 1024;       // float4 index 0..6143
    const int r  = g / 192;
    const int d4 = g - r * 192;
    float4 v = reinterpret_cast<const float4*>(hist)[g];
    if (d4 == 0 || d4 == 64 || d4 == 128) v.x = 0.0f;
    *reinterpret_cast<float4*>(&rows[r][d4 * 4]) = v;
  }
  __syncthreads();

  // row norms: 32 threads per row
  {
    const int r = tid >> 5, l = tid & 31;
    float s = 0.0f;
    #pragma unroll
    for (int k = 0; k < 6; ++k) {
      const float4 v = *reinterpret_cast<const float4*>(&rows[r][(l + 32 * k) * 4]);
      s += v.x * v.x + v.y * v.y + v.z * v.z + v.w * v.w;
    }
    s += __shfl_xor(s, 16); s += __shfl_xor(s, 8); s += __shfl_xor(s, 4);
    s += __shfl_xor(s, 2);  s += __shfl_xor(s, 1);
    if (l == 0) invn[r] = 1.0f / (sqrtf(s) + 1e-8f);
  }
  __syncthreads();

  // 240 upper-triangle pairs (sim symmetric -> x2), 4 threads per pair
  float pacc = 0.0f, nacc = 0.0f;
  if (tid < 960) {
    const int pr = tid >> 2, q = tid & 3;
    const int n = pr / 120;
    int rem = pr - n * 120;
    int i = 0, cnt = 15;
    while (rem >= cnt) { rem -= cnt; --cnt; ++i; }
    const int j = i + 1 + rem;
    // local row i = kp*SF + sf  ->  hist row = n*16 + sf*8 + kp
    const int gi = n * 16 + ((i & 1) << 3) + (i >> 1);
    const int gj = n * 16 + ((j & 1) << 3) + (j >> 1);
    const float* ri = rows[gi];
    const float* rj = rows[gj];
    float s = 0.0f;
    #pragma unroll
    for (int m = 0; m < 48; ++m) {
      const int d = q * 192 + m * 4;
      const float4 a = *reinterpret_cast<const float4*>(ri + d);
      const float4 bb = *reinterpret_cast<const float4*>(rj + d);
      s += a.x * bb.x + a.y * bb.y + a.z * bb.z + a.w * bb.w;
    }
    s += __shfl_xor(s, 1);
    s += __shfl_xor(s, 2);
    if (q == 0) {
      const float sim = s * invn[gi] * invn[gj];
      if ((i >> 1) == (j >> 1)) pacc = 2.0f * (1.0f - sim);      // same kp
      else                      nacc = 2.0f * fmaxf(sim - 0.5f, 0.0f);
    }
  }

  const int lane = tid & 63, w = tid >> 6;
  #pragma unroll
  for (int m = 32; m >= 1; m >>= 1) {
    pacc += __shfl_xor(pacc, m);
    nacc += __shfl_xor(nacc, m);
  }
  if (lane == 0) { wred[w][0] = pacc; wred[w][1] = nacc; }
  __syncthreads();
  if (tid == 0) {
    float p = 0.0f, g = 0.0f;
    #pragma unroll
    for (int w2 = 0; w2 < 16; ++w2) { p += wred[w2][0]; g += wred[w2][1]; }
    out[0] = p * (1.0f / 32.0f) + g * (1.0f / 448.0f);   // n_pos=32, n_neg=448
  }
}

extern "C" void kernel_launch(void* const* d_in, const int* in_sizes, int n_in,
                              void* d_out, int out_size, void* d_ws, size_t ws_size,
                              hipStream_t stream) {
  const float* coords = (const float*)d_in[0];
  const float* images = (const float*)d_in[1];
  float* hist = (float*)d_ws;            // 32*3*256 floats = 96 KB, fully overwritten
  float* out  = (float*)d_out;

  dim3 g1(C_, B_);
  pcl_hist<<<g1, 256, 0, stream>>>(coords, images, hist);
  pcl_loss<<<1, 1024, 0, stream>>>(hist, out);
}

// Round 3
// 44.387 us; speedup vs baseline: 2.4171x; 1.2665x over previous
//
#include <hip/hip_runtime.h>
#include <math.h>

namespace {
constexpr int NBINS_ = 256;
constexpr int C_   = 3;
constexpr int B_   = 32;     // N*SF*KP patches
constexpr int PIX_ = 4096;   // 64*64
constexpr int NPAIR_ = 272;  // 240 cross-pairs + 32 self-dots (norms)
constexpr float XEPS = 1e-7f;
// sigmoid((x - t/256)/0.001) = 1/(1+exp2((t - 256x) * ESC)), ESC = 1000/256 * log2(e)
constexpr float ESC = 5.63552750f;
constexpr float MSC = 0.0200374311f;   // log2(e)/72  (gaussian, std=6)
}

__device__ __forceinline__ float sig_edge(float t_minus_u) {
  float e = __builtin_amdgcn_exp2f(t_minus_u * ESC);
  return __builtin_amdgcn_rcpf(1.0f + e);
}

// row index helpers: local row i = kp*SF + sf -> global hist row sf*8 + kp
__device__ __forceinline__ int grow(int n, int i) {
  return n * 16 + ((i & 1) << 3) + (i >> 1);
}

// ---------------------------------------------------------------------------
// Kernel A: one block per (b, c). Fused gaussian mask * image -> scatter into
// per-wave LDS histograms (telescoped edge sigmoids, +-5 bin window).
// Near-zero pixels (x < 1e-7) are batched: count * k(0) applied once per wave.
// ---------------------------------------------------------------------------
__global__ __launch_bounds__(256) void pcl_hist(const float* __restrict__ coords,
                                                const float* __restrict__ images,
                                                float* __restrict__ hist) {
  __shared__ float shist[4][NBINS_];

  const int c   = blockIdx.x;          // 0..2
  const int b   = blockIdx.y;          // 0..31 = (n*SF+sf)*KP + kp
  const int tid = threadIdx.x;
  const int wv  = tid >> 6;
  const int lane = tid & 63;

  const float cx = coords[b * 2 + 0] * 64.0f;
  const float cy = coords[b * 2 + 1] * 64.0f;
  const int sfn = b >> 3;
  const float* img = images + (size_t)(sfn * C_ + c) * PIX_;

  shist[0][tid] = 0.0f; shist[1][tid] = 0.0f;
  shist[2][tid] = 0.0f; shist[3][tid] = 0.0f;
  __syncthreads();

  const float dx = (float)(tid & 63) - cx;
  const float dx2 = dx * dx;
  int zc = 0;

  for (int i = 0; i < 16; ++i) {
    const float py = (float)(i * 4 + wv);
    const float dy = py - cy;
    const float m = __builtin_amdgcn_exp2f(-(dx2 + dy * dy) * MSC);
    const float x = img[i * 256 + tid] * m;
    if (x < XEPS) {
      ++zc;
    } else {
      const float u = x * 256.0f;          // position in bin units
      int jc = (int)u; if (jc > 255) jc = 255;
      const int jlo = jc - 5;
      float eprev = sig_edge((float)jlo - u);
      #pragma unroll
      for (int s = 1; s <= 11; ++s) {
        const float e = sig_edge((float)(jlo + s) - u);
        const int bin = jlo + s - 1;
        if (bin >= 0 && bin < 256) atomicAdd(&shist[wv][bin], eprev - e);
        eprev = e;
      }
    }
  }

  // batched contribution of near-zero pixels: zf * (E_t(0) - E_{t+1}(0))
  float zf = (float)zc;
  #pragma unroll
  for (int m = 32; m >= 1; m >>= 1) zf += __shfl_xor(zf, m);
  {
    const float E = sig_edge((float)lane);       // edge t = lane at x = 0
    const float En = __shfl_down(E, 1);
    if (lane < 6) atomicAdd(&shist[wv][lane], zf * (E - En));
  }
  __syncthreads();

  hist[(size_t)(b * C_ + c) * NBINS_ + tid] =
      shist[0][tid] + shist[1][tid] + shist[2][tid] + shist[3][tid];
}

// ---------------------------------------------------------------------------
// Kernel B: one WAVE per pair (240 cross + 32 self). Rows read straight from
// global (hist = 96 KB -> L2-resident). Bin-0 slots (float4 .x at lane 0)
// zeroed at load. Raw dot written to dots[p]; normalization deferred.
// ---------------------------------------------------------------------------
__global__ __launch_bounds__(256) void pcl_dots(const float* __restrict__ hist,
                                                float* __restrict__ dots) {
  const int w = threadIdx.x >> 6, l = threadIdx.x & 63;
  const int p = blockIdx.x * 4 + w;
  if (p >= NPAIR_) return;

  int gi, gj;
  if (p < 240) {
    const int n = p / 120;
    int rem = p - n * 120;
    int i = 0, cnt = 15;
    while (rem >= cnt) { rem -= cnt; --cnt; ++i; }
    const int j = i + 1 + rem;
    gi = grow(n, i);
    gj = grow(n, j);
  } else {
    gi = gj = p - 240;                 // self-dot, global row index
  }

  const float4* A  = reinterpret_cast<const float4*>(hist + (size_t)gi * 768);
  const float4* Bv = reinterpret_cast<const float4*>(hist + (size_t)gj * 768);
  float s = 0.0f;
  #pragma unroll
  for (int k = 0; k < 3; ++k) {
    const int d4 = l + 64 * k;         // d4 in {0,64,128} iff l == 0
    float4 a = A[d4];
    float4 b = Bv[d4];
    if (l == 0) { a.x = 0.0f; b.x = 0.0f; }
    s += a.x * b.x + a.y * b.y + a.z * b.z + a.w * b.w;
  }
  #pragma unroll
  for (int m = 32; m >= 1; m >>= 1) s += __shfl_xor(s, m);
  if (l == 0) dots[p] = s;
}

// ---------------------------------------------------------------------------
// Kernel C: single small block. sim = dot_ij / ((sqrt(d_ii)+eps)(sqrt(d_jj)+eps))
// == cosine sim of bin0-zeroed rows. Contrastive reduce.
// ---------------------------------------------------------------------------
__global__ __launch_bounds__(256) void pcl_final(const float* __restrict__ dots,
                                                 float* __restrict__ out) {
  __shared__ float invn[B_];
  __shared__ float wred[4][2];
  const int tid = threadIdx.x;

  if (tid < B_) invn[tid] = 1.0f / (sqrtf(dots[240 + tid]) + 1e-8f);
  __syncthreads();

  float pacc = 0.0f, nacc = 0.0f;
  if (tid < 240) {
    const int n = tid / 120;
    int rem = tid - n * 120;
    int i = 0, cnt = 15;
    while (rem >= cnt) { rem -= cnt; --cnt; ++i; }
    const int j = i + 1 + rem;
    const float sim = dots[tid] * invn[grow(n, i)] * invn[grow(n, j)];
    if ((i >> 1) == (j >> 1)) pacc = 2.0f * (1.0f - sim);      // same kp, diff sf
    else                      nacc = 2.0f * fmaxf(sim - 0.5f, 0.0f);
  }

  const int lane = tid & 63, w = tid >> 6;
  #pragma unroll
  for (int m = 32; m >= 1; m >>= 1) {
    pacc += __shfl_xor(pacc, m);
    nacc += __shfl_xor(nacc, m);
  }
  if (lane == 0) { wred[w][0] = pacc; wred[w][1] = nacc; }
  __syncthreads();
  if (tid == 0) {
    float p = 0.0f, g = 0.0f;
    #pragma unroll
    for (int w2 = 0; w2 < 4; ++w2) { p += wred[w2][0]; g += wred[w2][1]; }
    out[0] = p * (1.0f / 32.0f) + g * (1.0f / 448.0f);   // n_pos=32, n_neg=448
  }
}

extern "C" void kernel_launch(void* const* d_in, const int* in_sizes, int n_in,
                              void* d_out, int out_size, void* d_ws, size_t ws_size,
                              hipStream_t stream) {
  const float* coords = (const float*)d_in[0];
  const float* images = (const float*)d_in[1];
  float* hist = (float*)d_ws;                        // 32*3*256 floats = 96 KB
  float* dots = (float*)d_ws + B_ * C_ * NBINS_;     // 272 floats
  float* out  = (float*)d_out;

  dim3 g1(C_, B_);
  pcl_hist<<<g1, 256, 0, stream>>>(coords, images, hist);
  pcl_dots<<<(NPAIR_ + 3) / 4, 256, 0, stream>>>(hist, dots);
  pcl_final<<<1, 256, 0, stream>>>(dots, out);
}

// Round 4
// 43.295 us; speedup vs baseline: 2.4781x; 1.0252x over previous
//
#include <hip/hip_runtime.h>
#include <math.h>

namespace {
constexpr int NBINS_ = 256;
constexpr int C_   = 3;
constexpr int B_   = 32;     // N*SF*KP patches (== global row index n*16 + sf*8 + kp)
constexpr int PIX_ = 4096;   // 64*64
constexpr int S_   = 2;      // row-split of each (b,c) hist across blocks
constexpr int HALF4_ = 6144; // float4 elements per partial half (96*256/4)
constexpr float XEPS = 1e-7f;
// sigmoid((x - t/256)/0.001) = 1/(1+exp2((t - 256x) * ESC)), ESC = 1000/256 * log2(e)
constexpr float ESC = 5.63552750f;
constexpr float MSC = 0.0200374311f;   // log2(e)/72  (gaussian, std=6)
constexpr int PADD_ = 776;             // LDS row stride (floats), 16B aligned
}

__device__ __forceinline__ float sig_edge(float t_minus_u) {
  const float e = __builtin_amdgcn_exp2f(t_minus_u * ESC);
  return __builtin_amdgcn_rcpf(1.0f + e);
}

// local row i = kp*SF + sf -> global hist row sf*8 + kp (within image n)
__device__ __forceinline__ int grow(int n, int i) {
  return n * 16 + ((i & 1) << 3) + (i >> 1);
}

// ---------------------------------------------------------------------------
// Kernel A: grid (C, B, S). Fused gaussian mask * image -> per-wave LDS
// histograms, telescoped edge sigmoids (+-3 bin window, guard slots kill the
// bounds branches). Near-zero pixels batched as count * k(0). Each block
// writes its 256-bin partial to part[s][b][c][:].
// ---------------------------------------------------------------------------
__global__ __launch_bounds__(256) void pcl_hist(const float* __restrict__ coords,
                                                const float* __restrict__ images,
                                                float* __restrict__ part) {
  __shared__ float sh[4][272];           // 8 guard slots each side

  const int c   = blockIdx.x;            // 0..2
  const int b   = blockIdx.y;            // 0..31
  const int s   = blockIdx.z;            // 0..1 (row halves)
  const int tid = threadIdx.x;
  const int wv  = tid >> 6;
  const int lane = tid & 63;

  const float cx = coords[b * 2 + 0] * 64.0f;
  const float cy = coords[b * 2 + 1] * 64.0f;
  const int sfn = b >> 3;
  const float* img = images + (size_t)(sfn * C_ + c) * PIX_;

  for (int k = tid; k < 4 * 272; k += 256) ((float*)sh)[k] = 0.0f;
  __syncthreads();

  const float dx = (float)lane - cx;
  const float dx2 = dx * dx;
  int zc = 0;

  for (int ii = 0; ii < 8; ++ii) {
    const int i = s * 8 + ii;
    const float dy = (float)(i * 4 + wv) - cy;
    const float m = __builtin_amdgcn_exp2f(-(dx2 + dy * dy) * MSC);
    const float x = img[i * 256 + tid] * m;
    if (x < XEPS) {
      ++zc;
    } else {
      const float u = x * 256.0f;        // position in bin units
      int jc = (int)u; if (jc > 255) jc = 255;
      const int jlo = jc - 3;
      const float fj = (float)jlo;
      float eprev = sig_edge(fj - u);
      #pragma unroll
      for (int t = 1; t <= 7; ++t) {
        const float e = sig_edge(fj + (float)t - u);
        atomicAdd(&sh[wv][8 + jlo + t - 1], eprev - e);  // guards absorb OOB
        eprev = e;
      }
    }
  }

  // batched near-zero pixels: zf * (E_t(0) - E_{t+1}(0)) for bins 0..5
  float zf = (float)zc;
  #pragma unroll
  for (int m = 32; m >= 1; m >>= 1) zf += __shfl_xor(zf, m);
  {
    const float E  = sig_edge((float)lane);
    const float En = __shfl_down(E, 1);
    if (lane < 6) atomicAdd(&sh[wv][8 + lane], zf * (E - En));
  }
  __syncthreads();

  part[((size_t)s * 96 + b * C_ + c) * NBINS_ + tid] =
      sh[0][8 + tid] + sh[1][8 + tid] + sh[2][8 + tid] + sh[3][8 + tid];
}

// ---------------------------------------------------------------------------
// Kernel B: single 1024-thread block. Stage both partial halves into LDS
// (summed, bin-0 zeroed), 32-thread row norms, one wave per cross-pair
// (normalized sim at write), contrastive reduce.
// ---------------------------------------------------------------------------
__global__ __launch_bounds__(1024) void pcl_loss(const float* __restrict__ part,
                                                 float* __restrict__ out) {
  __shared__ float rows[B_][PADD_];      // ~99.3 KB
  __shared__ float invn[B_];
  __shared__ float sdots[240];
  __shared__ float wred[16][2];

  const int tid = threadIdx.x;
  const int w = tid >> 6, l = tid & 63;

  // stage: sum the two partials, zero bin-0 slots (d4 = 0, 64, 128)
  const float4* h4 = reinterpret_cast<const float4*>(part);
  #pragma unroll
  for (int k = 0; k < 6; ++k) {
    const int g  = tid + k * 1024;       // float4 index 0..6143
    const int r  = g / 192;
    const int d4 = g - r * 192;
    const float4 a = h4[g];
    const float4 bb = h4[HALF4_ + g];
    float4 v;
    v.x = a.x + bb.x; v.y = a.y + bb.y; v.z = a.z + bb.z; v.w = a.w + bb.w;
    if (d4 == 0 || d4 == 64 || d4 == 128) v.x = 0.0f;
    *reinterpret_cast<float4*>(&rows[r][d4 * 4]) = v;
  }
  __syncthreads();

  // row norms: 32 threads per row
  {
    const int r = tid >> 5, l5 = tid & 31;
    float s = 0.0f;
    #pragma unroll
    for (int k = 0; k < 6; ++k) {
      const float4 v = *reinterpret_cast<const float4*>(&rows[r][(l5 + 32 * k) * 4]);
      s += v.x * v.x + v.y * v.y + v.z * v.z + v.w * v.w;
    }
    s += __shfl_xor(s, 16); s += __shfl_xor(s, 8); s += __shfl_xor(s, 4);
    s += __shfl_xor(s, 2);  s += __shfl_xor(s, 1);
    if (l5 == 0) invn[r] = 1.0f / (sqrtf(s) + 1e-8f);
  }
  __syncthreads();

  // 240 cross-pairs, one wave each (15 per wave x 16 waves)
  #pragma unroll
  for (int pp = 0; pp < 15; ++pp) {
    const int p = w * 15 + pp;
    const int n = p / 120;
    int rem = p - n * 120;
    int i = 0, cnt = 15;
    while (rem >= cnt) { rem -= cnt; --cnt; ++i; }
    const int j = i + 1 + rem;
    const int gi = grow(n, i);
    const int gj = grow(n, j);
    float s = 0.0f;
    #pragma unroll
    for (int k = 0; k < 3; ++k) {
      const int d4 = l + 64 * k;
      const float4 a  = *reinterpret_cast<const float4*>(&rows[gi][d4 * 4]);
      const float4 bb = *reinterpret_cast<const float4*>(&rows[gj][d4 * 4]);
      s += a.x * bb.x + a.y * bb.y + a.z * bb.z + a.w * bb.w;
    }
    #pragma unroll
    for (int m = 32; m >= 1; m >>= 1) s += __shfl_xor(s, m);
    if (l == 0) sdots[p] = s * invn[gi] * invn[gj];   // normalized sim
  }
  __syncthreads();

  // contrastive reduce
  float pacc = 0.0f, nacc = 0.0f;
  if (tid < 240) {
    const int n = tid / 120;
    int rem = tid - n * 120;
    int i = 0, cnt = 15;
    while (rem >= cnt) { rem -= cnt; --cnt; ++i; }
    const int j = i + 1 + rem;
    const float sim = sdots[tid];
    if ((i >> 1) == (j >> 1)) pacc = 2.0f * (1.0f - sim);      // same kp, diff sf
    else                      nacc = 2.0f * fmaxf(sim - 0.5f, 0.0f);
  }
  #pragma unroll
  for (int m = 32; m >= 1; m >>= 1) {
    pacc += __shfl_xor(pacc, m);
    nacc += __shfl_xor(nacc, m);
  }
  if (l == 0) { wred[w][0] = pacc; wred[w][1] = nacc; }
  __syncthreads();
  if (tid == 0) {
    float p = 0.0f, g = 0.0f;
    #pragma unroll
    for (int w2 = 0; w2 < 16; ++w2) { p += wred[w2][0]; g += wred[w2][1]; }
    out[0] = p * (1.0f / 32.0f) + g * (1.0f / 448.0f);   // n_pos=32, n_neg=448
  }
}

extern "C" void kernel_launch(void* const* d_in, const int* in_sizes, int n_in,
                              void* d_out, int out_size, void* d_ws, size_t ws_size,
                              hipStream_t stream) {
  const float* coords = (const float*)d_in[0];
  const float* images = (const float*)d_in[1];
  float* part = (float*)d_ws;            // [2][96][256] floats = 192 KB, fully overwritten
  float* out  = (float*)d_out;

  dim3 g1(C_, B_, S_);
  pcl_hist<<<g1, 256, 0, stream>>>(coords, images, part);
  pcl_loss<<<1, 1024, 0, stream>>>(part, out);
}